// Round 1
// baseline (864.779 us; speedup 1.0000x reference)
//
#include <hip/hip_runtime.h>
#include <hip/hip_bf16.h>

// GCN: h = relu(spmm(x@W1)+b1); h = relu(spmm(h@W2)+b2); out = spmm(h@W3)+b3
// spmm: out[r] = sum_{e: rows[e]==r} vals[e] * h[cols[e]]
//
// Strategy R0: device-built CSR (hist/scan/scatter) + tiled fp32 GEMM
// (128x128 tile, 8x8 microtile) + row-per-wave SpMM with float4 gathers.

#define N_NODES 50000
#define N_EDGES 800000

// ---------------- CSR build ----------------

__global__ void hist_kernel(const int* __restrict__ rows, int* __restrict__ counts, int ne) {
    int e = blockIdx.x * blockDim.x + threadIdx.x;
    if (e < ne) atomicAdd(&counts[rows[e]], 1);
}

// Single-block chunked Hillis-Steele exclusive scan over n counts -> row_ptr[n+1].
// Also zeroes counts for reuse by scatter.
__global__ void scan_kernel(int* __restrict__ counts, int* __restrict__ row_ptr, int n) {
    __shared__ int sdata[1024];
    __shared__ int carry;
    int tid = threadIdx.x;
    if (tid == 0) carry = 0;
    __syncthreads();
    for (int base = 0; base < n; base += 1024) {
        int i = base + tid;
        int v = (i < n) ? counts[i] : 0;
        sdata[tid] = v;
        __syncthreads();
        #pragma unroll
        for (int off = 1; off < 1024; off <<= 1) {
            int t = (tid >= off) ? sdata[tid - off] : 0;
            __syncthreads();
            sdata[tid] += t;
            __syncthreads();
        }
        int incl = sdata[tid];
        if (i < n) {
            row_ptr[i] = carry + (incl - v);
            counts[i] = 0;
        }
        __syncthreads();
        if (tid == 1023) carry += sdata[1023];
        __syncthreads();
    }
    if (tid == 0) row_ptr[n] = carry;
}

__global__ void scatter_kernel(const int* __restrict__ rows, const int* __restrict__ cols,
                               const float* __restrict__ vals, const int* __restrict__ rp,
                               int* __restrict__ counts, int* __restrict__ cs,
                               float* __restrict__ vs, int ne) {
    int e = blockIdx.x * blockDim.x + threadIdx.x;
    if (e < ne) {
        int r = rows[e];
        int pos = rp[r] + atomicAdd(&counts[r], 1);
        cs[pos] = cols[e];
        vs[pos] = vals[e];
    }
}

// ---------------- GEMM: C[M,N] = A[M,K] @ B[K,N], fp32 ----------------
// 128x128 block tile, BK=8, 256 threads, 8x8 per-thread microtile.

#define BM 128
#define BN 128
#define BK 8

__global__ __launch_bounds__(256) void gemm_kernel(
        const float* __restrict__ A, const float* __restrict__ B,
        float* __restrict__ C, int M, int N, int K) {
    __shared__ float As[BK][BM];   // transposed A tile
    __shared__ float Bs[BK][BN];

    int t  = threadIdx.x;
    int tx = t & 15;       // 0..15 -> col group
    int ty = t >> 4;       // 0..15 -> row group
    int row0 = blockIdx.x * BM;
    int col0 = blockIdx.y * BN;

    // A-tile load map: one float4 per thread: 128 rows x 8 cols
    int arow = t >> 1;            // 0..127
    int acol = (t & 1) * 4;       // 0 or 4
    // B-tile load map: one float4 per thread: 8 rows x 128 cols
    int brow = t >> 5;            // 0..7
    int bcol = (t & 31) * 4;      // 0..124

    float acc[8][8];
    #pragma unroll
    for (int i = 0; i < 8; i++)
        #pragma unroll
        for (int j = 0; j < 8; j++) acc[i][j] = 0.f;

    for (int k0 = 0; k0 < K; k0 += BK) {
        float4 a4;
        int gr = row0 + arow;
        if (gr < M) a4 = *(const float4*)&A[gr * K + k0 + acol];
        else        a4 = make_float4(0.f, 0.f, 0.f, 0.f);
        As[acol + 0][arow] = a4.x;
        As[acol + 1][arow] = a4.y;
        As[acol + 2][arow] = a4.z;
        As[acol + 3][arow] = a4.w;

        float4 b4 = *(const float4*)&B[(k0 + brow) * N + col0 + bcol];
        *(float4*)&Bs[brow][bcol] = b4;
        __syncthreads();

        #pragma unroll
        for (int k = 0; k < BK; k++) {
            float a[8], b[8];
            *(float4*)&a[0] = *(float4*)&As[k][ty * 8];
            *(float4*)&a[4] = *(float4*)&As[k][ty * 8 + 4];
            *(float4*)&b[0] = *(float4*)&Bs[k][tx * 8];
            *(float4*)&b[4] = *(float4*)&Bs[k][tx * 8 + 4];
            #pragma unroll
            for (int i = 0; i < 8; i++)
                #pragma unroll
                for (int j = 0; j < 8; j++)
                    acc[i][j] += a[i] * b[j];
        }
        __syncthreads();
    }

    #pragma unroll
    for (int i = 0; i < 8; i++) {
        int gr = row0 + ty * 8 + i;
        if (gr < M) {
            *(float4*)&C[gr * N + col0 + tx * 8]     = make_float4(acc[i][0], acc[i][1], acc[i][2], acc[i][3]);
            *(float4*)&C[gr * N + col0 + tx * 8 + 4] = make_float4(acc[i][4], acc[i][5], acc[i][6], acc[i][7]);
        }
    }
}

// ---------------- SpMM (CSR), fused bias (+ReLU) ----------------
// One wave per row; lane l handles F/64 consecutive features (float4 for F=256).

template <int F>
__global__ __launch_bounds__(256) void spmm_kernel(
        const float* __restrict__ H, const int* __restrict__ rp,
        const int* __restrict__ cs, const float* __restrict__ vs,
        const float* __restrict__ bias, float* __restrict__ out,
        int nrows, int relu) {
    constexpr int VEC = F / 64;
    int wave = threadIdx.x >> 6;
    int lane = threadIdx.x & 63;
    int r = blockIdx.x * 4 + wave;
    if (r >= nrows) return;

    float acc[VEC];
    #pragma unroll
    for (int j = 0; j < VEC; j++) acc[j] = 0.f;

    int start = rp[r], end = rp[r + 1];
    for (int e = start; e < end; e++) {
        int c = cs[e];
        float v = vs[e];
        const float* hp = &H[c * F + lane * VEC];
        #pragma unroll
        for (int j = 0; j < VEC; j++) acc[j] += v * hp[j];
    }

    #pragma unroll
    for (int j = 0; j < VEC; j++) {
        float o = acc[j] + bias[lane * VEC + j];
        if (relu) o = fmaxf(o, 0.f);
        out[r * F + lane * VEC + j] = o;
    }
}

// ---------------- launch ----------------

extern "C" void kernel_launch(void* const* d_in, const int* in_sizes, int n_in,
                              void* d_out, int out_size, void* d_ws, size_t ws_size,
                              hipStream_t stream) {
    const float* x    = (const float*)d_in[0];
    const float* av   = (const float*)d_in[1];
    const int*   rows = (const int*)d_in[2];
    const int*   cols = (const int*)d_in[3];
    const float* W1   = (const float*)d_in[4];
    const float* b1   = (const float*)d_in[5];
    const float* W2   = (const float*)d_in[6];
    const float* b2   = (const float*)d_in[7];
    const float* W3   = (const float*)d_in[8];
    const float* b3   = (const float*)d_in[9];
    float* out = (float*)d_out;

    const int N = N_NODES, E = N_EDGES;

    // workspace carve-up (256B aligned chunks); total ~109.3 MB
    char* p = (char*)d_ws;
    auto carve = [&](size_t bytes) {
        void* q = (void*)p;
        p += (bytes + 255) & ~(size_t)255;
        return q;
    };
    float* bufA   = (float*)carve((size_t)N * 256 * 4);
    float* bufB   = (float*)carve((size_t)N * 256 * 4);
    int*   rp     = (int*)carve((size_t)(N + 1) * 4);
    int*   counts = (int*)carve((size_t)N * 4);
    int*   cs     = (int*)carve((size_t)E * 4);
    float* vs     = (float*)carve((size_t)E * 4);

    // --- CSR build ---
    hipMemsetAsync(counts, 0, (size_t)N * 4, stream);
    hist_kernel<<<(E + 255) / 256, 256, 0, stream>>>(rows, counts, E);
    scan_kernel<<<1, 1024, 0, stream>>>(counts, rp, N);
    scatter_kernel<<<(E + 255) / 256, 256, 0, stream>>>(rows, cols, av, rp, counts, cs, vs, E);

    dim3 g2(( N + BM - 1) / BM, 256 / BN);   // (391, 2)
    dim3 g1(( N + BM - 1) / BM, 128 / BN);   // (391, 1)
    int spmm_blocks = (N + 3) / 4;

    // layer 1
    gemm_kernel<<<g2, 256, 0, stream>>>(x, W1, bufA, N, 256, 256);
    spmm_kernel<256><<<spmm_blocks, 256, 0, stream>>>(bufA, rp, cs, vs, b1, bufB, N, 1);
    // layer 2
    gemm_kernel<<<g2, 256, 0, stream>>>(bufB, W2, bufA, N, 256, 256);
    spmm_kernel<256><<<spmm_blocks, 256, 0, stream>>>(bufA, rp, cs, vs, b2, bufB, N, 1);
    // layer 3
    gemm_kernel<<<g1, 256, 0, stream>>>(bufB, W3, bufA, N, 128, 256);
    spmm_kernel<128><<<spmm_blocks, 256, 0, stream>>>(bufA, rp, cs, vs, b3, out, N, 0);
}

// Round 2
// 448.006 us; speedup vs baseline: 1.9303x; 1.9303x over previous
//
#include <hip/hip_runtime.h>
#include <hip/hip_bf16.h>

// GCN R1: bf16 MFMA GEMM (16x16x32, 128x128 tile) + bf16-gather SpMM.
// Pipeline: cast x->bf16, transpose-cast W->Wt bf16, CSR build,
//   [gemm_bf16 -> spmm(bias,relu)] x2, gemm_bf16 -> spmm(bias) fp32 out.

#define N_NODES 50000
#define N_EDGES 800000
#define KDIM 256

typedef __attribute__((ext_vector_type(8))) short short8;
typedef __attribute__((ext_vector_type(4))) float f32x4;

__device__ __forceinline__ ushort f2bf(float f) {
    union { float f; unsigned u; } x; x.f = f;
    unsigned r = x.u + 0x7fffu + ((x.u >> 16) & 1u);  // RTN-even
    return (ushort)(r >> 16);
}
__device__ __forceinline__ float bf2f(ushort u) {
    union { unsigned u; float f; } x; x.u = ((unsigned)u) << 16;
    return x.f;
}

// ---------------- casts ----------------

__global__ __launch_bounds__(256) void cast_x_kernel(const float* __restrict__ x,
                                                     ushort* __restrict__ xb, int n4) {
    int i = blockIdx.x * blockDim.x + threadIdx.x;
    if (i < n4) {
        float4 v = *(const float4*)&x[i * 4];
        ushort4 o;
        o.x = f2bf(v.x); o.y = f2bf(v.y); o.z = f2bf(v.z); o.w = f2bf(v.w);
        *(ushort4*)&xb[i * 4] = o;
    }
}

// Wt[n*K + k] = bf16(W[k*N + n]);  K=256, N in {256,128}. Tiny.
__global__ __launch_bounds__(256) void transpose_w_kernel(const float* __restrict__ W,
                                                          ushort* __restrict__ Wt, int Ndim) {
    int id = blockIdx.x * blockDim.x + threadIdx.x;   // over Ndim*KDIM
    if (id < Ndim * KDIM) {
        int nrow = id >> 8;          // /256
        int k    = id & 255;
        Wt[nrow * KDIM + k] = f2bf(W[k * Ndim + nrow]);
    }
}

// ---------------- CSR build ----------------

__global__ void hist_kernel(const int* __restrict__ rows, int* __restrict__ counts, int ne) {
    int e = blockIdx.x * blockDim.x + threadIdx.x;
    if (e < ne) atomicAdd(&counts[rows[e]], 1);
}

// single-block exclusive scan, shfl-based (2 barriers per 1024-chunk)
__global__ __launch_bounds__(1024) void scan_kernel(int* __restrict__ counts,
                                                    int* __restrict__ rp, int n) {
    __shared__ int wsum[16];
    __shared__ int carry;
    int tid = threadIdx.x, lane = tid & 63, wv = tid >> 6;
    if (tid == 0) carry = 0;
    __syncthreads();
    for (int base = 0; base < n; base += 1024) {
        int i = base + tid;
        int v = (i < n) ? counts[i] : 0;
        int incl = v;
        #pragma unroll
        for (int off = 1; off < 64; off <<= 1) {
            int t = __shfl_up(incl, off, 64);
            if (lane >= off) incl += t;
        }
        if (lane == 63) wsum[wv] = incl;
        __syncthreads();
        int wo = 0;
        #pragma unroll
        for (int j = 0; j < 15; j++) wo += (j < wv) ? wsum[j] : 0;
        if (i < n) { rp[i] = carry + wo + incl - v; counts[i] = 0; }
        __syncthreads();
        if (tid == 1023) carry += wo + incl;
        __syncthreads();
    }
    if (tid == 0) rp[n] = carry;
}

__global__ void scatter_kernel(const int* __restrict__ rows, const int* __restrict__ cols,
                               const float* __restrict__ vals, const int* __restrict__ rp,
                               int* __restrict__ counts, int* __restrict__ cs,
                               float* __restrict__ vs, int ne) {
    int e = blockIdx.x * blockDim.x + threadIdx.x;
    if (e < ne) {
        int r = rows[e];
        int pos = rp[r] + atomicAdd(&counts[r], 1);
        cs[pos] = cols[e];
        vs[pos] = vals[e];
    }
}

// ---------------- GEMM: C[M,N] = A[M,256] @ Wt[N,256]^T, bf16 in, bf16 out ----
// 128x128 tile, BK=32, 256 threads = 4 waves (2x2 of 64x64), 16x16x32 MFMA.

#define LDK 40   // padded k-stride in bf16 elems (80 B rows: 16B-aligned, conflict-light)

__global__ __launch_bounds__(256) void gemm_bf16_kernel(
        const ushort* __restrict__ A, const ushort* __restrict__ Wt,
        ushort* __restrict__ C, int M, int N) {
    __shared__ ushort As[128 * LDK];
    __shared__ ushort Ws[128 * LDK];

    int t = threadIdx.x;
    int lane = t & 63;
    int w = t >> 6;
    int row0 = blockIdx.x * 128, col0 = blockIdx.y * 128;
    int wm = (w & 1) * 64, wn = (w >> 1) * 64;
    int q = lane >> 4, mi = lane & 15;

    // staging map: unit u in [0,512): tile-row u>>2, k-chunk (u&3)*8 (8 bf16 = 16 B)
    int r0 = t >> 2, kc = (t & 3) * 8;   // unit t; unit t+256 -> row r0+64

    f32x4 acc[4][4];
    #pragma unroll
    for (int i = 0; i < 4; i++)
        #pragma unroll
        for (int j = 0; j < 4; j++) acc[i][j] = (f32x4)0.f;

    for (int k0 = 0; k0 < KDIM; k0 += 32) {
        int ga0 = row0 + r0;       if (ga0 >= M) ga0 = M - 1;
        int ga1 = row0 + r0 + 64;  if (ga1 >= M) ga1 = M - 1;
        short8 a0 = *(const short8*)&A[ga0 * KDIM + k0 + kc];
        short8 a1 = *(const short8*)&A[ga1 * KDIM + k0 + kc];
        short8 b0 = *(const short8*)&Wt[(col0 + r0) * KDIM + k0 + kc];
        short8 b1 = *(const short8*)&Wt[(col0 + r0 + 64) * KDIM + k0 + kc];
        __syncthreads();
        *(short8*)&As[r0 * LDK + kc]        = a0;
        *(short8*)&As[(r0 + 64) * LDK + kc] = a1;
        *(short8*)&Ws[r0 * LDK + kc]        = b0;
        *(short8*)&Ws[(r0 + 64) * LDK + kc] = b1;
        __syncthreads();

        short8 af[4], bf[4];
        #pragma unroll
        for (int mt = 0; mt < 4; mt++)
            af[mt] = *(const short8*)&As[(wm + mt * 16 + mi) * LDK + q * 8];
        #pragma unroll
        for (int nt = 0; nt < 4; nt++)
            bf[nt] = *(const short8*)&Ws[(wn + nt * 16 + mi) * LDK + q * 8];
        #pragma unroll
        for (int mt = 0; mt < 4; mt++)
            #pragma unroll
            for (int nt = 0; nt < 4; nt++)
                acc[mt][nt] = __builtin_amdgcn_mfma_f32_16x16x32_bf16(
                    af[mt], bf[nt], acc[mt][nt], 0, 0, 0);
    }

    // C/D layout: col = lane&15, row = q*4 + reg
    #pragma unroll
    for (int mt = 0; mt < 4; mt++) {
        #pragma unroll
        for (int r = 0; r < 4; r++) {
            int grow = row0 + wm + mt * 16 + q * 4 + r;
            if (grow < M) {
                #pragma unroll
                for (int nt = 0; nt < 4; nt++) {
                    int gcol = col0 + wn + nt * 16 + mi;
                    C[grow * N + gcol] = f2bf(acc[mt][nt][r]);
                }
            }
        }
    }
}

// ---------------- SpMM (CSR) over bf16 H, fp32 accumulate ----------------
// wave per row; lane handles VEC=F/64 consecutive feats. Edge loop unrolled x4.

template <int F, bool RELU, bool OUT_BF16>
__global__ __launch_bounds__(256) void spmm_kernel(
        const ushort* __restrict__ H, const int* __restrict__ rp,
        const int* __restrict__ cs, const float* __restrict__ vs,
        const float* __restrict__ bias, void* __restrict__ out, int nrows) {
    constexpr int VEC = F / 64;
    int wave = threadIdx.x >> 6, lane = threadIdx.x & 63;
    int r = blockIdx.x * 4 + wave;
    if (r >= nrows) return;

    const ushort* Hl = H + lane * VEC;
    float acc[VEC];
    #pragma unroll
    for (int j = 0; j < VEC; j++) acc[j] = 0.f;

    int start = rp[r], end = rp[r + 1];
    int e = start;
    for (; e + 4 <= end; e += 4) {
        int   c0 = cs[e],     c1 = cs[e + 1], c2 = cs[e + 2], c3 = cs[e + 3];
        float v0 = vs[e],     v1 = vs[e + 1], v2 = vs[e + 2], v3 = vs[e + 3];
        ushort h0[VEC], h1[VEC], h2[VEC], h3[VEC];
        #pragma unroll
        for (int j = 0; j < VEC; j++) h0[j] = Hl[(size_t)c0 * F + j];
        #pragma unroll
        for (int j = 0; j < VEC; j++) h1[j] = Hl[(size_t)c1 * F + j];
        #pragma unroll
        for (int j = 0; j < VEC; j++) h2[j] = Hl[(size_t)c2 * F + j];
        #pragma unroll
        for (int j = 0; j < VEC; j++) h3[j] = Hl[(size_t)c3 * F + j];
        #pragma unroll
        for (int j = 0; j < VEC; j++)
            acc[j] += v0 * bf2f(h0[j]) + v1 * bf2f(h1[j])
                    + v2 * bf2f(h2[j]) + v3 * bf2f(h3[j]);
    }
    for (; e < end; e++) {
        int c = cs[e]; float v = vs[e];
        #pragma unroll
        for (int j = 0; j < VEC; j++) acc[j] += v * bf2f(Hl[(size_t)c * F + j]);
    }

    #pragma unroll
    for (int j = 0; j < VEC; j++) {
        float o = acc[j] + bias[lane * VEC + j];
        if (RELU) o = fmaxf(o, 0.f);
        acc[j] = o;
    }
    if (OUT_BF16) {
        ushort* ob = (ushort*)out + (size_t)r * F + lane * VEC;
        #pragma unroll
        for (int j = 0; j < VEC; j++) ob[j] = f2bf(acc[j]);
    } else {
        float* of = (float*)out + (size_t)r * F + lane * VEC;
        #pragma unroll
        for (int j = 0; j < VEC; j++) of[j] = acc[j];
    }
}

// ---------------- launch ----------------

extern "C" void kernel_launch(void* const* d_in, const int* in_sizes, int n_in,
                              void* d_out, int out_size, void* d_ws, size_t ws_size,
                              hipStream_t stream) {
    const float* x    = (const float*)d_in[0];
    const float* av   = (const float*)d_in[1];
    const int*   rows = (const int*)d_in[2];
    const int*   cols = (const int*)d_in[3];
    const float* W1   = (const float*)d_in[4];
    const float* b1   = (const float*)d_in[5];
    const float* W2   = (const float*)d_in[6];
    const float* b2   = (const float*)d_in[7];
    const float* W3   = (const float*)d_in[8];
    const float* b3   = (const float*)d_in[9];
    float* out = (float*)d_out;

    const int N = N_NODES, E = N_EDGES;

    char* p = (char*)d_ws;
    auto carve = [&](size_t bytes) {
        void* q = (void*)p;
        p += (bytes + 255) & ~(size_t)255;
        return q;
    };
    ushort* xb   = (ushort*)carve((size_t)N * 256 * 2);   // bf16 x
    ushort* bufG = (ushort*)carve((size_t)N * 256 * 2);   // gemm out
    ushort* bufH = (ushort*)carve((size_t)N * 256 * 2);   // spmm out
    ushort* Wt1  = (ushort*)carve((size_t)256 * 256 * 2);
    ushort* Wt2  = (ushort*)carve((size_t)256 * 256 * 2);
    ushort* Wt3  = (ushort*)carve((size_t)128 * 256 * 2);
    int*    rp     = (int*)carve((size_t)(N + 1) * 4);
    int*    counts = (int*)carve((size_t)N * 4);
    int*    cs     = (int*)carve((size_t)E * 4);
    float*  vs     = (float*)carve((size_t)E * 4);

    // prep: casts + CSR
    hipMemsetAsync(counts, 0, (size_t)N * 4, stream);
    cast_x_kernel<<<(N * 256 / 4 + 255) / 256, 256, 0, stream>>>(x, xb, N * 256 / 4);
    transpose_w_kernel<<<(256 * 256 + 255) / 256, 256, 0, stream>>>(W1, Wt1, 256);
    transpose_w_kernel<<<(256 * 256 + 255) / 256, 256, 0, stream>>>(W2, Wt2, 256);
    transpose_w_kernel<<<(128 * 256 + 255) / 256, 256, 0, stream>>>(W3, Wt3, 128);
    hist_kernel<<<(E + 255) / 256, 256, 0, stream>>>(rows, counts, E);
    scan_kernel<<<1, 1024, 0, stream>>>(counts, rp, N);
    scatter_kernel<<<(E + 255) / 256, 256, 0, stream>>>(rows, cols, av, rp, counts, cs, vs, E);

    dim3 g2((N + 127) / 128, 2);   // N=256 wide
    dim3 g1((N + 127) / 128, 1);   // N=128 wide
    int spmm_blocks = (N + 3) / 4;

    // layer 1
    gemm_bf16_kernel<<<g2, 256, 0, stream>>>(xb, Wt1, bufG, N, 256);
    spmm_kernel<256, true, true><<<spmm_blocks, 256, 0, stream>>>(bufG, rp, cs, vs, b1, bufH, N);
    // layer 2
    gemm_bf16_kernel<<<g2, 256, 0, stream>>>(bufH, Wt2, bufG, N, 256);
    spmm_kernel<256, true, true><<<spmm_blocks, 256, 0, stream>>>(bufG, rp, cs, vs, b2, bufH, N);
    // layer 3
    gemm_bf16_kernel<<<g1, 256, 0, stream>>>(bufH, Wt3, bufG, N, 128);
    spmm_kernel<128, false, false><<<spmm_blocks, 256, 0, stream>>>(bufG, rp, cs, vs, b3, out, N);
}

// Round 3
// 404.416 us; speedup vs baseline: 2.1383x; 1.1078x over previous
//
#include <hip/hip_runtime.h>
#include <hip/hip_bf16.h>

// GCN R2: packed int2 edges, wave-per-row multi-edge SpMM, hierarchical scan,
// cast fused into gemm1. bf16 MFMA GEMM (16x16x32, 128x128 tile).

#define N_NODES 50000
#define N_EDGES 800000
#define KDIM 256
#define NB_SCAN 49          // ceil(50000/1024)
#define COUNTS_PAD (NB_SCAN * 1024)

typedef __attribute__((ext_vector_type(8))) short short8;
typedef __attribute__((ext_vector_type(4))) float f32x4;

__device__ __forceinline__ ushort f2bf(float f) {
    union { float f; unsigned u; } x; x.f = f;
    unsigned r = x.u + 0x7fffu + ((x.u >> 16) & 1u);  // RTN-even
    return (ushort)(r >> 16);
}
__device__ __forceinline__ float bf2f(ushort u) {
    union { unsigned u; float f; } x; x.u = ((unsigned)u) << 16;
    return x.f;
}

// ---------------- weight transpose-cast ----------------
// Wt[n*K + k] = bf16(W[k*N + n]);  K=256.
__global__ __launch_bounds__(256) void transpose_w_kernel(const float* __restrict__ W,
                                                          ushort* __restrict__ Wt, int Ndim) {
    int id = blockIdx.x * blockDim.x + threadIdx.x;
    if (id < Ndim * KDIM) {
        int nrow = id >> 8;
        int k    = id & 255;
        Wt[nrow * KDIM + k] = f2bf(W[k * Ndim + nrow]);
    }
}

// ---------------- CSR build ----------------

__global__ void hist_kernel(const int* __restrict__ rows, int* __restrict__ counts, int ne) {
    int e = blockIdx.x * blockDim.x + threadIdx.x;
    if (e < ne) atomicAdd(&counts[rows[e]], 1);
}

// k1: per-block (1024 elems) sums
__global__ __launch_bounds__(256) void scan_sums(const int* __restrict__ counts,
                                                 int* __restrict__ bsum) {
    __shared__ int ws[4];
    int b = blockIdx.x, t = threadIdx.x, lane = t & 63, wv = t >> 6;
    int4 v = *(const int4*)&counts[b * 1024 + t * 4];
    int s = v.x + v.y + v.z + v.w;
    #pragma unroll
    for (int off = 32; off >= 1; off >>= 1) s += __shfl_down(s, off, 64);
    if (lane == 0) ws[wv] = s;
    __syncthreads();
    if (t == 0) bsum[b] = ws[0] + ws[1] + ws[2] + ws[3];
}

// k2: single-wave exclusive scan of block sums; also writes rp[n] = total
__global__ __launch_bounds__(64) void scan_block(const int* __restrict__ bsum,
                                                 int* __restrict__ boff,
                                                 int* __restrict__ rp, int nb, int n) {
    int t = threadIdx.x;
    int v = (t < nb) ? bsum[t] : 0;
    int incl = v;
    #pragma unroll
    for (int off = 1; off < 64; off <<= 1) {
        int u = __shfl_up(incl, off, 64);
        if (t >= off) incl += u;
    }
    if (t < nb) boff[t] = incl - v;
    if (t == 63) rp[n] = incl;
}

// k3: apply scan -> rp, zero counts for scatter reuse
__global__ __launch_bounds__(256) void scan_apply(int* __restrict__ counts,
                                                  const int* __restrict__ boff,
                                                  int* __restrict__ rp, int n) {
    __shared__ int ws[4];
    int b = blockIdx.x, t = threadIdx.x, lane = t & 63, wv = t >> 6;
    int i = b * 1024 + t * 4;
    int4 v = *(const int4*)&counts[i];
    int s0 = v.x, s01 = s0 + v.y, s012 = s01 + v.z, tsum = s012 + v.w;
    int incl = tsum;
    #pragma unroll
    for (int off = 1; off < 64; off <<= 1) {
        int u = __shfl_up(incl, off, 64);
        if (lane >= off) incl += u;
    }
    if (lane == 63) ws[wv] = incl;
    __syncthreads();
    int woff = 0;
    #pragma unroll
    for (int j = 0; j < 3; j++) woff += (j < wv) ? ws[j] : 0;
    int base = boff[b] + woff + incl - tsum;
    if (i < n)     rp[i]     = base;
    if (i + 1 < n) rp[i + 1] = base + s0;
    if (i + 2 < n) rp[i + 2] = base + s01;
    if (i + 3 < n) rp[i + 3] = base + s012;
    *(int4*)&counts[i] = make_int4(0, 0, 0, 0);
}

__global__ void scatter_kernel(const int* __restrict__ rows, const int* __restrict__ cols,
                               const float* __restrict__ vals, const int* __restrict__ rp,
                               int* __restrict__ counts, int2* __restrict__ cv, int ne) {
    int e = blockIdx.x * blockDim.x + threadIdx.x;
    if (e < ne) {
        int r = rows[e];
        int pos = rp[r] + atomicAdd(&counts[r], 1);
        cv[pos] = make_int2(cols[e], __float_as_int(vals[e]));
    }
}

// ---------------- GEMM: C[M,N] = A[M,256] @ Wt[N,256]^T, bf16 out ----------
// 128x128 tile, BK=32, 256 threads = 4 waves (2x2 of 64x64), 16x16x32 MFMA.
// AFP32: A is fp32, cast during staging (layer-1 fusion of the x cast).

#define LDK 40

template <bool AFP32>
__global__ __launch_bounds__(256) void gemm_bf16_kernel(
        const void* __restrict__ Ain, const ushort* __restrict__ Wt,
        ushort* __restrict__ C, int M, int N) {
    __shared__ ushort As[128 * LDK];
    __shared__ ushort Ws[128 * LDK];

    int t = threadIdx.x;
    int lane = t & 63;
    int w = t >> 6;
    int row0 = blockIdx.x * 128, col0 = blockIdx.y * 128;
    int wm = (w & 1) * 64, wn = (w >> 1) * 64;
    int q = lane >> 4, mi = lane & 15;

    int r0 = t >> 2, kc = (t & 3) * 8;

    f32x4 acc[4][4];
    #pragma unroll
    for (int i = 0; i < 4; i++)
        #pragma unroll
        for (int j = 0; j < 4; j++) acc[i][j] = (f32x4)0.f;

    for (int k0 = 0; k0 < KDIM; k0 += 32) {
        int ga0 = row0 + r0;       if (ga0 >= M) ga0 = M - 1;
        int ga1 = row0 + r0 + 64;  if (ga1 >= M) ga1 = M - 1;
        short8 a0, a1;
        if (AFP32) {
            const float* Af = (const float*)Ain;
            float4 f0 = *(const float4*)&Af[ga0 * KDIM + k0 + kc];
            float4 f1 = *(const float4*)&Af[ga0 * KDIM + k0 + kc + 4];
            float4 f2 = *(const float4*)&Af[ga1 * KDIM + k0 + kc];
            float4 f3 = *(const float4*)&Af[ga1 * KDIM + k0 + kc + 4];
            a0[0] = (short)f2bf(f0.x); a0[1] = (short)f2bf(f0.y);
            a0[2] = (short)f2bf(f0.z); a0[3] = (short)f2bf(f0.w);
            a0[4] = (short)f2bf(f1.x); a0[5] = (short)f2bf(f1.y);
            a0[6] = (short)f2bf(f1.z); a0[7] = (short)f2bf(f1.w);
            a1[0] = (short)f2bf(f2.x); a1[1] = (short)f2bf(f2.y);
            a1[2] = (short)f2bf(f2.z); a1[3] = (short)f2bf(f2.w);
            a1[4] = (short)f2bf(f3.x); a1[5] = (short)f2bf(f3.y);
            a1[6] = (short)f2bf(f3.z); a1[7] = (short)f2bf(f3.w);
        } else {
            const ushort* Ab = (const ushort*)Ain;
            a0 = *(const short8*)&Ab[ga0 * KDIM + k0 + kc];
            a1 = *(const short8*)&Ab[ga1 * KDIM + k0 + kc];
        }
        short8 b0 = *(const short8*)&Wt[(col0 + r0) * KDIM + k0 + kc];
        short8 b1 = *(const short8*)&Wt[(col0 + r0 + 64) * KDIM + k0 + kc];
        __syncthreads();
        *(short8*)&As[r0 * LDK + kc]        = a0;
        *(short8*)&As[(r0 + 64) * LDK + kc] = a1;
        *(short8*)&Ws[r0 * LDK + kc]        = b0;
        *(short8*)&Ws[(r0 + 64) * LDK + kc] = b1;
        __syncthreads();

        short8 af[4], bf[4];
        #pragma unroll
        for (int mt = 0; mt < 4; mt++)
            af[mt] = *(const short8*)&As[(wm + mt * 16 + mi) * LDK + q * 8];
        #pragma unroll
        for (int nt = 0; nt < 4; nt++)
            bf[nt] = *(const short8*)&Ws[(wn + nt * 16 + mi) * LDK + q * 8];
        #pragma unroll
        for (int mt = 0; mt < 4; mt++)
            #pragma unroll
            for (int nt = 0; nt < 4; nt++)
                acc[mt][nt] = __builtin_amdgcn_mfma_f32_16x16x32_bf16(
                    af[mt], bf[nt], acc[mt][nt], 0, 0, 0);
    }

    // C/D layout: col = lane&15, row = q*4 + reg
    #pragma unroll
    for (int mt = 0; mt < 4; mt++) {
        #pragma unroll
        for (int r = 0; r < 4; r++) {
            int grow = row0 + wm + mt * 16 + q * 4 + r;
            if (grow < M) {
                #pragma unroll
                for (int nt = 0; nt < 4; nt++) {
                    int gcol = col0 + wn + nt * 16 + mi;
                    C[grow * N + gcol] = f2bf(acc[mt][nt][r]);
                }
            }
        }
    }
}

// ---------------- SpMM (CSR): wave per row, EP edges in parallel ----------
// Lane = ep*FL + fl: fl indexes 8 consecutive feats (16B load), ep the edge slot.
// Cross-ep reduction via shfl_down, then bias(+relu), store by group 0.

template <int F, bool RELU, bool OUT_BF16>
__global__ __launch_bounds__(256) void spmm_kernel(
        const ushort* __restrict__ H, const int* __restrict__ rp,
        const int2* __restrict__ cv, const float* __restrict__ bias,
        void* __restrict__ out, int nrows) {
    constexpr int FL = F / 8;      // feature lanes: 32 (F=256) / 16 (F=128)
    constexpr int EP = 64 / FL;    // parallel edges: 2 / 4
    int wave = threadIdx.x >> 6, lane = threadIdx.x & 63;
    int r = blockIdx.x * 4 + wave;
    if (r >= nrows) return;
    int fl = lane % FL, ep = lane / FL;
    const ushort* Hl = H + fl * 8;

    float acc[8];
    #pragma unroll
    for (int j = 0; j < 8; j++) acc[j] = 0.f;

    int start = rp[r], end = rp[r + 1];
    for (int base = start; base < end; base += 2 * EP) {
        int e0 = base + ep, e1 = base + EP + ep;
        bool p0 = e0 < end, p1 = e1 < end;
        int2 m0 = p0 ? cv[e0] : make_int2(0, 0);
        int2 m1 = p1 ? cv[e1] : make_int2(0, 0);
        float v0 = __int_as_float(m0.y);
        float v1 = __int_as_float(m1.y);
        short8 h0 = *(const short8*)&Hl[(size_t)m0.x * F];
        short8 h1 = *(const short8*)&Hl[(size_t)m1.x * F];
        #pragma unroll
        for (int j = 0; j < 8; j++)
            acc[j] += v0 * bf2f((ushort)h0[j]) + v1 * bf2f((ushort)h1[j]);
    }

    // reduce across edge groups (same fl, different ep)
    #pragma unroll
    for (int off = FL; off < 64; off <<= 1)
        #pragma unroll
        for (int j = 0; j < 8; j++) acc[j] += __shfl_down(acc[j], off, 64);

    if (ep == 0) {
        #pragma unroll
        for (int j = 0; j < 8; j++) {
            float o = acc[j] + bias[fl * 8 + j];
            if (RELU) o = fmaxf(o, 0.f);
            acc[j] = o;
        }
        if (OUT_BF16) {
            short8 ob;
            #pragma unroll
            for (int j = 0; j < 8; j++) ob[j] = (short)f2bf(acc[j]);
            *(short8*)((ushort*)out + (size_t)r * F + fl * 8) = ob;
        } else {
            float* of = (float*)out + (size_t)r * F + fl * 8;
            *(float4*)&of[0] = make_float4(acc[0], acc[1], acc[2], acc[3]);
            *(float4*)&of[4] = make_float4(acc[4], acc[5], acc[6], acc[7]);
        }
    }
}

// ---------------- launch ----------------

extern "C" void kernel_launch(void* const* d_in, const int* in_sizes, int n_in,
                              void* d_out, int out_size, void* d_ws, size_t ws_size,
                              hipStream_t stream) {
    const float* x    = (const float*)d_in[0];
    const float* av   = (const float*)d_in[1];
    const int*   rows = (const int*)d_in[2];
    const int*   cols = (const int*)d_in[3];
    const float* W1   = (const float*)d_in[4];
    const float* b1   = (const float*)d_in[5];
    const float* W2   = (const float*)d_in[6];
    const float* b2   = (const float*)d_in[7];
    const float* W3   = (const float*)d_in[8];
    const float* b3   = (const float*)d_in[9];
    float* out = (float*)d_out;

    const int N = N_NODES, E = N_EDGES;

    char* p = (char*)d_ws;
    auto carve = [&](size_t bytes) {
        void* q = (void*)p;
        p += (bytes + 255) & ~(size_t)255;
        return q;
    };
    ushort* bufG = (ushort*)carve((size_t)N * 256 * 2);
    ushort* bufH = (ushort*)carve((size_t)N * 256 * 2);
    ushort* Wt1  = (ushort*)carve((size_t)256 * 256 * 2);
    ushort* Wt2  = (ushort*)carve((size_t)256 * 256 * 2);
    ushort* Wt3  = (ushort*)carve((size_t)128 * 256 * 2);
    int*    rp     = (int*)carve((size_t)(N + 1) * 4);
    int*    counts = (int*)carve((size_t)COUNTS_PAD * 4);
    int*    bsum   = (int*)carve((size_t)NB_SCAN * 4);
    int*    boff   = (int*)carve((size_t)NB_SCAN * 4);
    int2*   cv     = (int2*)carve((size_t)E * 8);

    // CSR build
    hipMemsetAsync(counts, 0, (size_t)COUNTS_PAD * 4, stream);
    transpose_w_kernel<<<(256 * 256 + 255) / 256, 256, 0, stream>>>(W1, Wt1, 256);
    transpose_w_kernel<<<(256 * 256 + 255) / 256, 256, 0, stream>>>(W2, Wt2, 256);
    transpose_w_kernel<<<(128 * 256 + 255) / 256, 256, 0, stream>>>(W3, Wt3, 128);
    hist_kernel<<<(E + 255) / 256, 256, 0, stream>>>(rows, counts, E);
    scan_sums<<<NB_SCAN, 256, 0, stream>>>(counts, bsum);
    scan_block<<<1, 64, 0, stream>>>(bsum, boff, rp, NB_SCAN, N);
    scan_apply<<<NB_SCAN, 256, 0, stream>>>(counts, boff, rp, N);
    scatter_kernel<<<(E + 255) / 256, 256, 0, stream>>>(rows, cols, av, rp, counts, cv, E);

    dim3 g2((N + 127) / 128, 2);
    dim3 g1((N + 127) / 128, 1);
    int spmm_blocks = (N + 3) / 4;

    // layer 1 (x fp32 cast fused into gemm staging)
    gemm_bf16_kernel<true><<<g2, 256, 0, stream>>>(x, Wt1, bufG, N, 256);
    spmm_kernel<256, true, true><<<spmm_blocks, 256, 0, stream>>>(bufG, rp, cv, b1, bufH, N);
    // layer 2
    gemm_bf16_kernel<false><<<g2, 256, 0, stream>>>(bufH, Wt2, bufG, N, 256);
    spmm_kernel<256, true, true><<<spmm_blocks, 256, 0, stream>>>(bufG, rp, cv, b2, bufH, N);
    // layer 3
    gemm_bf16_kernel<false><<<g1, 256, 0, stream>>>(bufH, Wt3, bufG, N, 128);
    spmm_kernel<128, false, false><<<spmm_blocks, 256, 0, stream>>>(bufG, rp, cv, b3, out, N);
}

// Round 4
// 373.213 us; speedup vs baseline: 2.3171x; 1.0836x over previous
//
#include <hip/hip_runtime.h>
#include <hip/hip_bf16.h>

// GCN R3: 8x-replicated CSR counters (atomic contention /8), spmm with 4
// gathers in flight per lane, hist fused into gemm1, merged transposes.

#define N_NODES 50000
#define N_EDGES 800000
#define KDIM 256
#define REP 8
#define NC (N_NODES * REP)            // 400000 replicated counters
#define NB2 ((NC + 1023) / 1024)      // 391 scan blocks
#define NC_PAD (NB2 * 1024)           // 400384

typedef __attribute__((ext_vector_type(8))) short short8;
typedef __attribute__((ext_vector_type(4))) float f32x4;

__device__ __forceinline__ ushort f2bf(float f) {
    union { float f; unsigned u; } x; x.f = f;
    unsigned r = x.u + 0x7fffu + ((x.u >> 16) & 1u);  // RTN-even
    return (ushort)(r >> 16);
}
__device__ __forceinline__ float bf2f(ushort u) {
    union { unsigned u; float f; } x; x.u = ((unsigned)u) << 16;
    return x.f;
}

// ---------------- merged weight transpose-casts ----------------
// Wt[n*256 + k] = bf16(W[k*N + n]) for W1(256x256), W2(256x256), W3(256x128)
__global__ __launch_bounds__(256) void transpose_all_kernel(
        const float* __restrict__ W1, const float* __restrict__ W2,
        const float* __restrict__ W3, ushort* __restrict__ Wt1,
        ushort* __restrict__ Wt2, ushort* __restrict__ Wt3) {
    int id = blockIdx.x * blockDim.x + threadIdx.x;
    if (id < 65536) {
        int n = id >> 8, k = id & 255;
        Wt1[n * 256 + k] = f2bf(W1[k * 256 + n]);
    } else if (id < 131072) {
        int i = id - 65536, n = i >> 8, k = i & 255;
        Wt2[n * 256 + k] = f2bf(W2[k * 256 + n]);
    } else if (id < 163840) {
        int i = id - 131072, n = i >> 8, k = i & 255;
        Wt3[n * 256 + k] = f2bf(W3[k * 128 + n]);
    }
}

// ---------------- GEMM body: C[M,N] = A[M,256] @ Wt[N,256]^T, bf16 out ------
// 128x128 tile, BK=32, 256 threads = 4 waves (2x2 of 64x64), 16x16x32 MFMA.

#define LDK 40

template <bool AFP32>
__device__ __forceinline__ void gemm_body(
        const void* __restrict__ Ain, const ushort* __restrict__ Wt,
        ushort* __restrict__ C, int M, int N, int bx, int by) {
    __shared__ ushort As[128 * LDK];
    __shared__ ushort Ws[128 * LDK];

    int t = threadIdx.x;
    int lane = t & 63;
    int w = t >> 6;
    int row0 = bx * 128, col0 = by * 128;
    int wm = (w & 1) * 64, wn = (w >> 1) * 64;
    int q = lane >> 4, mi = lane & 15;
    int r0 = t >> 2, kc = (t & 3) * 8;

    f32x4 acc[4][4];
    #pragma unroll
    for (int i = 0; i < 4; i++)
        #pragma unroll
        for (int j = 0; j < 4; j++) acc[i][j] = (f32x4)0.f;

    for (int k0 = 0; k0 < KDIM; k0 += 32) {
        int ga0 = row0 + r0;       if (ga0 >= M) ga0 = M - 1;
        int ga1 = row0 + r0 + 64;  if (ga1 >= M) ga1 = M - 1;
        short8 a0, a1;
        if (AFP32) {
            const float* Af = (const float*)Ain;
            float4 f0 = *(const float4*)&Af[ga0 * KDIM + k0 + kc];
            float4 f1 = *(const float4*)&Af[ga0 * KDIM + k0 + kc + 4];
            float4 f2 = *(const float4*)&Af[ga1 * KDIM + k0 + kc];
            float4 f3 = *(const float4*)&Af[ga1 * KDIM + k0 + kc + 4];
            a0[0] = (short)f2bf(f0.x); a0[1] = (short)f2bf(f0.y);
            a0[2] = (short)f2bf(f0.z); a0[3] = (short)f2bf(f0.w);
            a0[4] = (short)f2bf(f1.x); a0[5] = (short)f2bf(f1.y);
            a0[6] = (short)f2bf(f1.z); a0[7] = (short)f2bf(f1.w);
            a1[0] = (short)f2bf(f2.x); a1[1] = (short)f2bf(f2.y);
            a1[2] = (short)f2bf(f2.z); a1[3] = (short)f2bf(f2.w);
            a1[4] = (short)f2bf(f3.x); a1[5] = (short)f2bf(f3.y);
            a1[6] = (short)f2bf(f3.z); a1[7] = (short)f2bf(f3.w);
        } else {
            const ushort* Ab = (const ushort*)Ain;
            a0 = *(const short8*)&Ab[ga0 * KDIM + k0 + kc];
            a1 = *(const short8*)&Ab[ga1 * KDIM + k0 + kc];
        }
        short8 b0 = *(const short8*)&Wt[(col0 + r0) * KDIM + k0 + kc];
        short8 b1 = *(const short8*)&Wt[(col0 + r0 + 64) * KDIM + k0 + kc];
        __syncthreads();
        *(short8*)&As[r0 * LDK + kc]        = a0;
        *(short8*)&As[(r0 + 64) * LDK + kc] = a1;
        *(short8*)&Ws[r0 * LDK + kc]        = b0;
        *(short8*)&Ws[(r0 + 64) * LDK + kc] = b1;
        __syncthreads();

        short8 af[4], bf[4];
        #pragma unroll
        for (int mt = 0; mt < 4; mt++)
            af[mt] = *(const short8*)&As[(wm + mt * 16 + mi) * LDK + q * 8];
        #pragma unroll
        for (int nt = 0; nt < 4; nt++)
            bf[nt] = *(const short8*)&Ws[(wn + nt * 16 + mi) * LDK + q * 8];
        #pragma unroll
        for (int mt = 0; mt < 4; mt++)
            #pragma unroll
            for (int nt = 0; nt < 4; nt++)
                acc[mt][nt] = __builtin_amdgcn_mfma_f32_16x16x32_bf16(
                    af[mt], bf[nt], acc[mt][nt], 0, 0, 0);
    }

    // C/D layout: col = lane&15, row = q*4 + reg
    #pragma unroll
    for (int mt = 0; mt < 4; mt++) {
        #pragma unroll
        for (int r = 0; r < 4; r++) {
            int grow = row0 + wm + mt * 16 + q * 4 + r;
            if (grow < M) {
                #pragma unroll
                for (int nt = 0; nt < 4; nt++) {
                    int gcol = col0 + wn + nt * 16 + mi;
                    C[grow * N + gcol] = f2bf(acc[mt][nt][r]);
                }
            }
        }
    }
}

// layer-1 gemm (fp32 A, fused cast) + hist in one fat kernel.
// blocks [0, GB1): gemm tiles; blocks [GB1, GB1+3125): hist.
#define GB1 782   // 391 row-tiles x 2 col-tiles

__global__ __launch_bounds__(256) void gemm1_hist_kernel(
        const float* __restrict__ x, const ushort* __restrict__ Wt1,
        ushort* __restrict__ C, const int* __restrict__ rows,
        int* __restrict__ counts) {
    int b = blockIdx.x;
    if (b < GB1) {
        gemm_body<true>(x, Wt1, C, N_NODES, 256, b % 391, b / 391);
    } else {
        int e = (b - GB1) * 256 + threadIdx.x;
        if (e < N_EDGES) {
            int r = rows[e];
            atomicAdd(&counts[(r << 3) | (e & 7)], 1);
        }
    }
}

template <bool AFP32>
__global__ __launch_bounds__(256) void gemm_bf16_kernel(
        const void* __restrict__ Ain, const ushort* __restrict__ Wt,
        ushort* __restrict__ C, int M, int N) {
    gemm_body<AFP32>(Ain, Wt, C, M, N, blockIdx.x, blockIdx.y);
}

// ---------------- hierarchical scan over NC replicated counters ------------

__global__ __launch_bounds__(256) void scan_sums(const int* __restrict__ counts,
                                                 int* __restrict__ bsum) {
    __shared__ int ws[4];
    int b = blockIdx.x, t = threadIdx.x, lane = t & 63, wv = t >> 6;
    int4 v = *(const int4*)&counts[b * 1024 + t * 4];
    int s = v.x + v.y + v.z + v.w;
    #pragma unroll
    for (int off = 32; off >= 1; off >>= 1) s += __shfl_down(s, off, 64);
    if (lane == 0) ws[wv] = s;
    __syncthreads();
    if (t == 0) bsum[b] = ws[0] + ws[1] + ws[2] + ws[3];
}

// single block, 512 threads: exclusive scan of NB2 block sums; writes total.
__global__ __launch_bounds__(512) void scan_block(const int* __restrict__ bsum,
                                                  int* __restrict__ boff,
                                                  int* __restrict__ rp8, int nb) {
    __shared__ int ws[8];
    int t = threadIdx.x, lane = t & 63, wv = t >> 6;
    int v = (t < nb) ? bsum[t] : 0;
    int incl = v;
    #pragma unroll
    for (int off = 1; off < 64; off <<= 1) {
        int u = __shfl_up(incl, off, 64);
        if (lane >= off) incl += u;
    }
    if (lane == 63) ws[wv] = incl;
    __syncthreads();
    int wo = 0;
    #pragma unroll
    for (int j = 0; j < 7; j++) wo += (j < wv) ? ws[j] : 0;
    if (t < nb) boff[t] = wo + incl - v;
    if (t == 511) rp8[NC] = wo + incl;   // == N_EDGES
}

__global__ __launch_bounds__(256) void scan_apply(int* __restrict__ counts,
                                                  const int* __restrict__ boff,
                                                  int* __restrict__ rp8) {
    __shared__ int ws[4];
    int b = blockIdx.x, t = threadIdx.x, lane = t & 63, wv = t >> 6;
    int i = b * 1024 + t * 4;
    int4 v = *(const int4*)&counts[i];
    int s0 = v.x, s01 = s0 + v.y, s012 = s01 + v.z, tsum = s012 + v.w;
    int incl = tsum;
    #pragma unroll
    for (int off = 1; off < 64; off <<= 1) {
        int u = __shfl_up(incl, off, 64);
        if (lane >= off) incl += u;
    }
    if (lane == 63) ws[wv] = incl;
    __syncthreads();
    int woff = 0;
    #pragma unroll
    for (int j = 0; j < 3; j++) woff += (j < wv) ? ws[j] : 0;
    int base = boff[b] + woff + incl - tsum;
    if (i < NC)     rp8[i]     = base;
    if (i + 1 < NC) rp8[i + 1] = base + s0;
    if (i + 2 < NC) rp8[i + 2] = base + s01;
    if (i + 3 < NC) rp8[i + 3] = base + s012;
    *(int4*)&counts[i] = make_int4(0, 0, 0, 0);
}

__global__ void scatter_kernel(const int* __restrict__ rows, const int* __restrict__ cols,
                               const float* __restrict__ vals, const int* __restrict__ rp8,
                               int* __restrict__ counts, int2* __restrict__ cv) {
    int e = blockIdx.x * blockDim.x + threadIdx.x;
    if (e < N_EDGES) {
        int idx = (rows[e] << 3) | (e & 7);
        int pos = rp8[idx] + atomicAdd(&counts[idx], 1);
        cv[pos] = make_int2(cols[e], __float_as_int(vals[e]));
    }
}

// ---------------- SpMM (CSR): wave per row, EP edge-groups x 4 unroll ------
// Lane = ep*FL + fl; each ep group owns 4 contiguous edges per iteration ->
// 4 independent 16B gathers + 4 int2 meta loads in flight per lane.

template <int F, bool RELU, bool OUT_BF16>
__global__ __launch_bounds__(256) void spmm_kernel(
        const ushort* __restrict__ H, const int* __restrict__ rp8,
        const int2* __restrict__ cv, const float* __restrict__ bias,
        void* __restrict__ out, int nrows) {
    constexpr int FL = F / 8;       // 32 (F=256) / 16 (F=128)
    constexpr int EP = 64 / FL;     // 2 / 4
    constexpr int STEP = EP * 4;    // 8 / 16 edges per iteration
    int wave = threadIdx.x >> 6, lane = threadIdx.x & 63;
    int r = blockIdx.x * 4 + wave;
    if (r >= nrows) return;
    int fl = lane % FL, ep = lane / FL;
    const ushort* Hl = H + fl * 8;

    float acc[8];
    #pragma unroll
    for (int j = 0; j < 8; j++) acc[j] = 0.f;

    int start = rp8[r * REP], end = rp8[r * REP + REP];
    for (int base = start; base < end; base += STEP) {
        int e0 = base + ep * 4;
        int2 m0 = cv[e0], m1 = cv[e0 + 1], m2 = cv[e0 + 2], m3 = cv[e0 + 3];
        int   c0 = (e0     < end) ? m0.x : 0;
        int   c1 = (e0 + 1 < end) ? m1.x : 0;
        int   c2 = (e0 + 2 < end) ? m2.x : 0;
        int   c3 = (e0 + 3 < end) ? m3.x : 0;
        float v0 = (e0     < end) ? __int_as_float(m0.y) : 0.f;
        float v1 = (e0 + 1 < end) ? __int_as_float(m1.y) : 0.f;
        float v2 = (e0 + 2 < end) ? __int_as_float(m2.y) : 0.f;
        float v3 = (e0 + 3 < end) ? __int_as_float(m3.y) : 0.f;
        short8 h0 = *(const short8*)&Hl[(size_t)c0 * F];
        short8 h1 = *(const short8*)&Hl[(size_t)c1 * F];
        short8 h2 = *(const short8*)&Hl[(size_t)c2 * F];
        short8 h3 = *(const short8*)&Hl[(size_t)c3 * F];
        #pragma unroll
        for (int j = 0; j < 8; j++)
            acc[j] += v0 * bf2f((ushort)h0[j]) + v1 * bf2f((ushort)h1[j])
                    + v2 * bf2f((ushort)h2[j]) + v3 * bf2f((ushort)h3[j]);
    }

    #pragma unroll
    for (int off = FL; off < 64; off <<= 1)
        #pragma unroll
        for (int j = 0; j < 8; j++) acc[j] += __shfl_down(acc[j], off, 64);

    if (ep == 0) {
        #pragma unroll
        for (int j = 0; j < 8; j++) {
            float o = acc[j] + bias[fl * 8 + j];
            if (RELU) o = fmaxf(o, 0.f);
            acc[j] = o;
        }
        if (OUT_BF16) {
            short8 ob;
            #pragma unroll
            for (int j = 0; j < 8; j++) ob[j] = (short)f2bf(acc[j]);
            *(short8*)((ushort*)out + (size_t)r * F + fl * 8) = ob;
        } else {
            float* of = (float*)out + (size_t)r * F + fl * 8;
            *(float4*)&of[0] = make_float4(acc[0], acc[1], acc[2], acc[3]);
            *(float4*)&of[4] = make_float4(acc[4], acc[5], acc[6], acc[7]);
        }
    }
}

// ---------------- launch ----------------

extern "C" void kernel_launch(void* const* d_in, const int* in_sizes, int n_in,
                              void* d_out, int out_size, void* d_ws, size_t ws_size,
                              hipStream_t stream) {
    const float* x    = (const float*)d_in[0];
    const float* av   = (const float*)d_in[1];
    const int*   rows = (const int*)d_in[2];
    const int*   cols = (const int*)d_in[3];
    const float* W1   = (const float*)d_in[4];
    const float* b1   = (const float*)d_in[5];
    const float* W2   = (const float*)d_in[6];
    const float* b2   = (const float*)d_in[7];
    const float* W3   = (const float*)d_in[8];
    const float* b3   = (const float*)d_in[9];
    float* out = (float*)d_out;

    const int N = N_NODES, E = N_EDGES;

    char* p = (char*)d_ws;
    auto carve = [&](size_t bytes) {
        void* q = (void*)p;
        p += (bytes + 255) & ~(size_t)255;
        return q;
    };
    ushort* bufG = (ushort*)carve((size_t)N * 256 * 2);
    ushort* bufH = (ushort*)carve((size_t)N * 256 * 2);
    ushort* Wt1  = (ushort*)carve((size_t)256 * 256 * 2);
    ushort* Wt2  = (ushort*)carve((size_t)256 * 256 * 2);
    ushort* Wt3  = (ushort*)carve((size_t)128 * 256 * 2);
    int*    rp8    = (int*)carve((size_t)(NC + 1) * 4);
    int*    counts = (int*)carve((size_t)NC_PAD * 4);
    int*    bsum   = (int*)carve((size_t)NB2 * 4);
    int*    boff   = (int*)carve((size_t)NB2 * 4);
    int2*   cv     = (int2*)carve((size_t)(E + 16) * 8);

    hipMemsetAsync(counts, 0, (size_t)NC_PAD * 4, stream);
    transpose_all_kernel<<<(163840 + 255) / 256, 256, 0, stream>>>(W1, W2, W3, Wt1, Wt2, Wt3);

    // layer-1 gemm (compute-bound) overlapped with hist (latency-bound)
    gemm1_hist_kernel<<<GB1 + (E + 255) / 256, 256, 0, stream>>>(x, Wt1, bufG, rows, counts);

    scan_sums<<<NB2, 256, 0, stream>>>(counts, bsum);
    scan_block<<<1, 512, 0, stream>>>(bsum, boff, rp8, NB2);
    scan_apply<<<NB2, 256, 0, stream>>>(counts, boff, rp8);
    scatter_kernel<<<(E + 255) / 256, 256, 0, stream>>>(rows, cols, av, rp8, counts, cv);

    int spmm_blocks = (N + 3) / 4;
    spmm_kernel<256, true, true><<<spmm_blocks, 256, 0, stream>>>(bufG, rp8, cv, b1, bufH, N);
    gemm_bf16_kernel<false><<<dim3(391, 2), 256, 0, stream>>>(bufH, Wt2, bufG, N, 256);
    spmm_kernel<256, true, true><<<spmm_blocks, 256, 0, stream>>>(bufG, rp8, cv, b2, bufH, N);
    gemm_bf16_kernel<false><<<dim3(391, 1), 256, 0, stream>>>(bufH, Wt3, bufG, N, 128);
    spmm_kernel<128, false, false><<<spmm_blocks, 256, 0, stream>>>(bufG, rp8, cv, b3, out, N);
}